// Round 5
// baseline (540.936 us; speedup 1.0000x reference)
//
#include <hip/hip_runtime.h>
#include <hip/hip_bf16.h>

#define N_ATOMS 10000
#define N_PAIRS 100000
#define HH 64

// ---- expnormal rbf constants ----
constexpr float RBF_START = 0.6065306597126334f;               // exp(-0.5)
constexpr float RBF_STEP  = (1.0f - RBF_START) / 31.0f;        // linspace step
constexpr float RBF_BETA  = 1.0f / ((0.0625f * (1.0f - RBF_START)) * (0.0625f * (1.0f - RBF_START)));
constexpr float TWO_PI    = 6.2831853071795864f;

// ---- f32 param layout in workspace (element offsets) ----
#define OFF_EMB   0
#define OFF_W2    6400
#define OFF_B2    14592
#define OFF_D1W   14656
#define OFF_D1B   16704
#define OFF_D2W   16768
#define OFF_D2B   18816
#define OFF_D3W   18880
#define OFF_D3B   20928
#define OFF_LT0   20992
#define OFF_LT1   25088
#define OFF_LT2   29184
#define OFF_L1W   33280
#define OFF_L1B   41472
#define OFF_L2W   41600
#define OFF_L2B   66176
#define OFF_LNG   66368
#define OFF_LNB   66432
#define N_PARAMF  66496

// ws byte offsets
#define WS_WF     0
#define WS_CNT    266240
#define WS_OFF    306240
#define WS_CUR    346256
#define WS_PLIST  386256
#define WS_FLAGS  786256

__device__ __forceinline__ float bf2f(unsigned short u) {
    return __uint_as_float(((unsigned int)u) << 16);
}

// ---- on-device buffer layout probe ----
// returns 1 if buffer is a true bf16 (2-byte) array, 0 if f32 (4-byte) layout.
// bf16-ROUNDED f32 data has every low u16 == 0 -> all 32 even lanes zero -> f32.
// raw f32 data has random low halves -> many implausible bf16 exponents -> f32.
__device__ int classify64(const unsigned short* b, int lane) {
    unsigned short x = b[lane];
    int e = (x >> 7) & 0xFF;
    bool implaus = (x != 0) && (e < 96 || e > 133);
    bool zeroeven = ((lane & 1) == 0) && (x == 0);
    unsigned long long mi = __ballot(implaus);
    unsigned long long mz = __ballot(zeroeven);
    if (__popcll(mz) == 32) return 0;   // bf16-rounded f32 layout
    if (__popcll(mi) >= 8) return 0;    // raw f32 layout
    return 1;                           // true bf16 array
}

__global__ void k_probe(const unsigned short* emb_u, const unsigned short* dij_u,
                        const unsigned short* rij_u, int* flags) {
    int lane = threadIdx.x;
    int fp = classify64(emb_u, lane);
    int fd = classify64(dij_u, lane);
    int fr = classify64(rij_u, lane);
    if (lane == 0) { flags[0] = fp; flags[1] = fd; flags[2] = fr; }
}

struct ConvArgs { const void* src[18]; float* dst; };

__global__ void k_conv(ConvArgs a, const int* __restrict__ flags) {
    const int sizes[18] = {6400,8192,64,2048,64,2048,64,2048,64,4096,4096,4096,8192,128,24576,192,64,64};
    int t = blockIdx.x * 256 + threadIdx.x;
    if (t >= N_PARAMF) return;
    int acc = 0, seg = 0, off = t;
    #pragma unroll
    for (int i = 0; i < 18; ++i) {
        if (t >= acc && t < acc + sizes[i]) { seg = i; off = t - acc; }
        acc += sizes[i];
    }
    if (flags[0] == 1)
        a.dst[t] = bf2f(((const unsigned short*)a.src[seg])[off]);
    else
        a.dst[t] = ((const float*)a.src[seg])[off];
}

__global__ void k_count(const int* __restrict__ pidx, int* __restrict__ cnt) {
    int p = blockIdx.x * 256 + threadIdx.x;
    if (p < N_PAIRS) atomicAdd(&cnt[pidx[p]], 1);
}

__global__ void k_scan(const int* __restrict__ cnt, int* __restrict__ offs, int* __restrict__ cur) {
    __shared__ int buf[1024];
    int tid = threadIdx.x;
    int base = tid * 10;
    int c[10]; int s = 0;
    #pragma unroll
    for (int i = 0; i < 10; ++i) {
        int idx = base + i;
        int v = (idx < N_ATOMS) ? cnt[idx] : 0;
        c[i] = v; s += v;
    }
    buf[tid] = s;
    __syncthreads();
    for (int off = 1; off < 1024; off <<= 1) {
        int v = (tid >= off) ? buf[tid - off] : 0;
        __syncthreads();
        buf[tid] += v;
        __syncthreads();
    }
    int run = buf[tid] - s;  // exclusive prefix for this chunk
    #pragma unroll
    for (int i = 0; i < 10; ++i) {
        int idx = base + i;
        if (idx < N_ATOMS) { offs[idx] = run; cur[idx] = run; run += c[i]; }
    }
    if (tid == 0) offs[N_ATOMS] = N_PAIRS;
}

__global__ void k_fill(const int* __restrict__ pidx, int* __restrict__ cur, int* __restrict__ plist) {
    int p = blockIdx.x * 256 + threadIdx.x;
    if (p < N_PAIRS) {
        int s = pidx[p];
        int pos = atomicAdd(&cur[s], 1);
        plist[pos] = p;
    }
}

__device__ __forceinline__ float dot4(float4 a, float4 b) {
    return a.x*b.x + a.y*b.y + a.z*b.z + a.w*b.w;
}

__global__ __launch_bounds__(64) void k_atom(
    const int* __restrict__ an, const int* __restrict__ pidx,
    const void* __restrict__ dij_v, const void* __restrict__ rij_v,
    const float* __restrict__ WF,
    const int* __restrict__ offs, const int* __restrict__ plist,
    const int* __restrict__ flags,
    float* __restrict__ out)
{
    const int n = blockIdx.x;
    const int h = threadIdx.x;

    __shared__ __align__(16) float zsrc[64];
    __shared__ __align__(16) float zdst[64];
    __shared__ __align__(16) float rbf[32];
    __shared__ __align__(16) float nv[64];
    __shared__ __align__(16) float y1[128];
    __shared__ __align__(16) float y2[192];
    __shared__ __align__(16) float accL[640];
    __shared__ __align__(16) float ob[576];

    const bool dbf = (flags[1] == 1);
    const bool rbff = (flags[2] == 1);
    const float* dij_f = (const float*)dij_v;
    const float* rij_f = (const float*)rij_v;
    const unsigned short* dij_u = (const unsigned short*)dij_v;
    const unsigned short* rij_u = (const unsigned short*)rij_v;

    const float* emb = WF + OFF_EMB;

    zsrc[h] = emb[an[n] * HH + h];

    float Is=0.f, sx=0.f, sy=0.f, sz=0.f;
    float Sxx=0.f, Syy=0.f, Szz=0.f, Sxy=0.f, Sxz=0.f, Syz=0.f;

    const int pbeg = offs[n], pend = offs[n + 1];

    const float4* w2r = (const float4*)(WF + OFF_W2) + h * 32;  // row h: 32 float4
    const float4* d1r = (const float4*)(WF + OFF_D1W) + h * 8;
    const float4* d2r = (const float4*)(WF + OFF_D2W) + h * 8;
    const float4* d3r = (const float4*)(WF + OFF_D3W) + h * 8;
    const float eb2 = (WF + OFF_B2)[h];
    const float ed1 = (WF + OFF_D1B)[h];
    const float ed2 = (WF + OFF_D2B)[h];
    const float ed3 = (WF + OFF_D3B)[h];

    for (int ii = pbeg; ii < pend; ++ii) {
        int p = plist[ii];
        int dst = pidx[N_PAIRS + p];
        float d  = dbf  ? bf2f(dij_u[p])      : dij_f[p];
        float rx, ry, rz;
        if (rbff) { rx = bf2f(rij_u[3*p]); ry = bf2f(rij_u[3*p+1]); rz = bf2f(rij_u[3*p+2]); }
        else      { rx = rij_f[3*p];       ry = rij_f[3*p+1];       rz = rij_f[3*p+2]; }
        float inv = 1.0f / d;
        float ux = rx*inv, uy = ry*inv, uz = rz*inv;
        float rc = (d < 0.5f) ? 0.5f * (cosf(TWO_PI * d) + 1.0f) : 0.0f;

        zdst[h] = emb[an[dst] * HH + h];
        if (h < 32) {
            float en = expf(-10.0f * d);
            float t = en - (RBF_START + RBF_STEP * (float)h);
            rbf[h] = expf(-RBF_BETA * t * t) * rc;
        }
        __syncthreads();

        // Zij[h] = b2[h] + zij . w2_row_h   (zij = [zsrc | zdst])
        float zc = eb2;
        const float4* zs4 = (const float4*)zsrc;
        const float4* zd4 = (const float4*)zdst;
        #pragma unroll
        for (int k4 = 0; k4 < 16; ++k4) zc += dot4(w2r[k4],      zs4[k4]);
        #pragma unroll
        for (int k4 = 0; k4 < 16; ++k4) zc += dot4(w2r[16 + k4], zd4[k4]);

        float g1 = ed1, g2 = ed2, g3 = ed3;
        const float4* rb4 = (const float4*)rbf;
        #pragma unroll
        for (int r4 = 0; r4 < 8; ++r4) {
            float4 rb = rb4[r4];
            g1 += dot4(d1r[r4], rb);
            g2 += dot4(d2r[r4], rb);
            g3 += dot4(d3r[r4], rb);
        }
        float Cc = rc * zc;
        float f1 = g1 * Cc;
        float f2 = g2 * Cc * 10.0f;
        float f3 = g3 * Cc * 100.0f;

        Is += f1;
        sx += f2 * ux;  sy += f2 * uy;  sz += f2 * uz;
        float q = (ux*ux + uy*uy + uz*uz) * (1.0f / 3.0f);
        Sxx += f3 * (ux*ux - q);
        Syy += f3 * (uy*uy - q);
        Szz += f3 * (uz*uz - q);
        Sxy += f3 * (ux*uy);
        Sxz += f3 * (ux*uz);
        Syz += f3 * (uy*uz);
        __syncthreads();
    }

    // stage accumulators (c-major, h contiguous)
    accL[       h] = Is;
    accL[ 64  + h] = sx;  accL[128 + h] = sy;  accL[192 + h] = sz;
    accL[256 + h] = Sxx; accL[320 + h] = Syy; accL[384 + h] = Szz;
    accL[448 + h] = Sxy; accL[512 + h] = Sxz; accL[576 + h] = Syz;

    // tn = || I + A + S ||_F^2 per h (cross terms vanish)
    float tn = 3.0f*Is*Is + 2.0f*(sx*sx + sy*sy + sz*sz)
             + Sxx*Sxx + Syy*Syy + Szz*Szz
             + 2.0f*(Sxy*Sxy + Sxz*Sxz + Syz*Syz);

    // LayerNorm over h (single wave)
    float s1 = tn, s2 = tn * tn;
    #pragma unroll
    for (int o = 32; o > 0; o >>= 1) {
        s1 += __shfl_xor(s1, o);
        s2 += __shfl_xor(s2, o);
    }
    float mu  = s1 * (1.0f / 64.0f);
    float var = s2 * (1.0f / 64.0f) - mu * mu;
    float xh = (tn - mu) * rsqrtf(var + 1e-5f) * (WF + OFF_LNG)[h] + (WF + OFF_LNB)[h];
    nv[h] = xh;
    __syncthreads();

    // y1 = silu(nv @ ls1_w.T + ls1_b), 128 outs
    #pragma unroll
    for (int jj = 0; jj < 2; ++jj) {
        int j = h + 64 * jj;
        const float4* wr = (const float4*)(WF + OFF_L1W) + j * 16;
        const float4* x4 = (const float4*)nv;
        float acc = (WF + OFF_L1B)[j];
        #pragma unroll
        for (int k4 = 0; k4 < 16; ++k4) acc += dot4(wr[k4], x4[k4]);
        y1[j] = acc / (1.0f + expf(-acc));
    }
    __syncthreads();

    // y2 = silu(y1 @ ls2_w.T + ls2_b), 192 outs
    #pragma unroll
    for (int mm = 0; mm < 3; ++mm) {
        int m = h + 64 * mm;
        const float4* wr = (const float4*)(WF + OFF_L2W) + m * 32;
        const float4* x4 = (const float4*)y1;
        float acc = (WF + OFF_L2B)[m];
        #pragma unroll
        for (int k4 = 0; k4 < 32; ++k4) acc += dot4(wr[k4], x4[k4]);
        y2[m] = acc / (1.0f + expf(-acc));
    }
    __syncthreads();

    // final transform: g = h
    float n0 = y2[3*h], n1 = y2[3*h+1], n2 = y2[3*h+2];
    const float4* t0r = (const float4*)(WF + OFF_LT0) + h * 16;
    const float4* t1r = (const float4*)(WF + OFF_LT1) + h * 16;
    const float4* t2r = (const float4*)(WF + OFF_LT2) + h * 16;
    const float4* aI  = (const float4*)(accL);
    const float4* aAx = (const float4*)(accL + 64);
    const float4* aAy = (const float4*)(accL + 128);
    const float4* aAz = (const float4*)(accL + 192);
    const float4* aXX = (const float4*)(accL + 256);
    const float4* aYY = (const float4*)(accL + 320);
    const float4* aZZ = (const float4*)(accL + 384);
    const float4* aXY = (const float4*)(accL + 448);
    const float4* aXZ = (const float4*)(accL + 512);
    const float4* aYZ = (const float4*)(accL + 576);

    float P0=0.f, PAx=0.f, PAy=0.f, PAz=0.f;
    float Q0=0.f, Q1=0.f, Q2=0.f, Q3=0.f, Q4=0.f, Q5=0.f;
    #pragma unroll
    for (int k4 = 0; k4 < 16; ++k4) {
        float4 w0 = t0r[k4], w1 = t1r[k4], w2 = t2r[k4];
        P0  += dot4(w0, aI[k4]);
        PAx += dot4(w1, aAx[k4]);
        PAy += dot4(w1, aAy[k4]);
        PAz += dot4(w1, aAz[k4]);
        Q0  += dot4(w2, aXX[k4]);
        Q1  += dot4(w2, aYY[k4]);
        Q2  += dot4(w2, aZZ[k4]);
        Q3  += dot4(w2, aXY[k4]);
        Q4  += dot4(w2, aXZ[k4]);
        Q5  += dot4(w2, aYZ[k4]);
    }
    float Iv = P0 * n0;
    float Ax = PAx * n1, Ay = PAy * n1, Az = PAz * n1;
    float Xx = Q0 * n2, Yy = Q1 * n2, Zz = Q2 * n2;
    float Xy = Q3 * n2, Xz = Q4 * n2, Yz = Q5 * n2;

    float* o = ob + h * 9;
    o[0] =  Iv + Xx;  o[1] = -Az + Xy;  o[2] =  Ay + Xz;
    o[3] =  Az + Xy;  o[4] =  Iv + Yy;  o[5] = -Ax + Yz;
    o[6] = -Ay + Xz;  o[7] =  Ax + Yz;  o[8] =  Iv + Zz;
    __syncthreads();

    float* outp = out + (size_t)n * 576;
    #pragma unroll
    for (int t = h; t < 576; t += 64) outp[t] = ob[t];
}

extern "C" void kernel_launch(void* const* d_in, const int* in_sizes, int n_in,
                              void* d_out, int out_size, void* d_ws, size_t ws_size,
                              hipStream_t stream) {
    const int* an   = (const int*)d_in[0];
    const int* pidx = (const int*)d_in[1];

    char* ws = (char*)d_ws;
    float* WF    = (float*)(ws + WS_WF);
    int*   cnt   = (int*)(ws + WS_CNT);
    int*   offs  = (int*)(ws + WS_OFF);
    int*   cur   = (int*)(ws + WS_CUR);
    int*   plist = (int*)(ws + WS_PLIST);
    int*   flags = (int*)(ws + WS_FLAGS);
    float* out   = (float*)d_out;

    hipMemsetAsync(cnt, 0, N_ATOMS * sizeof(int), stream);

    k_probe<<<1, 64, 0, stream>>>((const unsigned short*)d_in[4],
                                  (const unsigned short*)d_in[2],
                                  (const unsigned short*)d_in[3], flags);

    ConvArgs ca;
    for (int i = 0; i < 18; ++i) ca.src[i] = d_in[4 + i];
    ca.dst = WF;
    k_conv<<<(N_PARAMF + 255) / 256, 256, 0, stream>>>(ca, flags);

    k_count<<<(N_PAIRS + 255) / 256, 256, 0, stream>>>(pidx, cnt);
    k_scan<<<1, 1024, 0, stream>>>(cnt, offs, cur);
    k_fill<<<(N_PAIRS + 255) / 256, 256, 0, stream>>>(pidx, cur, plist);
    k_atom<<<N_ATOMS, 64, 0, stream>>>(an, pidx, d_in[2], d_in[3], WF, offs, plist, flags, out);
}

// Round 6
// 439.716 us; speedup vs baseline: 1.2302x; 1.2302x over previous
//
#include <hip/hip_runtime.h>
#include <hip/hip_bf16.h>

#define N_ATOMS 10000
#define N_PAIRS 100000
#define HH 64
#define MAXZ 100

// ---- expnormal rbf constants ----
constexpr float RBF_START = 0.6065306597126334f;               // exp(-0.5)
constexpr float RBF_STEP  = (1.0f - RBF_START) / 31.0f;        // linspace step
constexpr float RBF_BETA  = 1.0f / ((0.0625f * (1.0f - RBF_START)) * (0.0625f * (1.0f - RBF_START)));
constexpr float TWO_PI    = 6.2831853071795864f;

// ---- f32 param layout in workspace (element offsets) ----
#define OFF_EMB   0
#define OFF_W2    6400
#define OFF_B2    14592
#define OFF_D1W   14656
#define OFF_D1B   16704
#define OFF_D2W   16768
#define OFF_D2B   18816
#define OFF_D3W   18880
#define OFF_D3B   20928
#define OFF_LT0   20992
#define OFF_LT1   25088
#define OFF_LT2   29184
#define OFF_L1W   33280
#define OFF_L1B   41472
#define OFF_L2W   41600
#define OFF_L2B   66176
#define OFF_LNG   66368
#define OFF_LNB   66432
#define N_PARAMF  66496

// ws byte offsets
#define WS_WF     0
#define WS_CNT    266240
#define WS_OFF    306240
#define WS_CUR    346256
#define WS_PLIST  386256
#define WS_FLAGS  786256
#define WS_T1     786432
#define WS_T2     (WS_T1 + MAXZ * HH * 4)

__device__ __forceinline__ float bf2f(unsigned short u) {
    return __uint_as_float(((unsigned int)u) << 16);
}

// ---- on-device buffer layout probe (see round 3/4 forensics) ----
__device__ int classify64(const unsigned short* b, int lane) {
    unsigned short x = b[lane];
    int e = (x >> 7) & 0xFF;
    bool implaus = (x != 0) && (e < 96 || e > 133);
    bool zeroeven = ((lane & 1) == 0) && (x == 0);
    unsigned long long mi = __ballot(implaus);
    unsigned long long mz = __ballot(zeroeven);
    if (__popcll(mz) == 32) return 0;   // bf16-rounded f32 layout
    if (__popcll(mi) >= 8) return 0;    // raw f32 layout
    return 1;                           // true bf16 array
}

__global__ void k_probe(const unsigned short* emb_u, const unsigned short* dij_u,
                        const unsigned short* rij_u, int* flags) {
    int lane = threadIdx.x;
    int fp = classify64(emb_u, lane);
    int fd = classify64(dij_u, lane);
    int fr = classify64(rij_u, lane);
    if (lane == 0) { flags[0] = fp; flags[1] = fd; flags[2] = fr; }
}

struct ConvArgs { const void* src[18]; float* dst; };

__global__ void k_conv(ConvArgs a, const int* __restrict__ flags) {
    const int sizes[18] = {6400,8192,64,2048,64,2048,64,2048,64,4096,4096,4096,8192,128,24576,192,64,64};
    int t = blockIdx.x * 256 + threadIdx.x;
    if (t >= N_PARAMF) return;
    int acc = 0, seg = 0, off = t;
    #pragma unroll
    for (int i = 0; i < 18; ++i) {
        if (t >= acc && t < acc + sizes[i]) { seg = i; off = t - acc; }
        acc += sizes[i];
    }
    if (flags[0] == 1)
        a.dst[t] = bf2f(((const unsigned short*)a.src[seg])[off]);
    else
        a.dst[t] = ((const float*)a.src[seg])[off];
}

// T1[z][h] = sum_k W2[h][k]*emb[z][k] (k<64); T2[z][h] = sum_k W2[h][64+k]*emb[z][k]
__global__ void k_tab(const float* __restrict__ WF, float* __restrict__ T1, float* __restrict__ T2) {
    int z = blockIdx.x;
    int h = threadIdx.x;
    const float* ez = WF + OFF_EMB + z * HH;
    const float* w2 = WF + OFF_W2 + h * 128;
    float s1 = 0.f, s2 = 0.f;
    #pragma unroll
    for (int k = 0; k < 64; ++k) {
        float e = ez[k];
        s1 += w2[k] * e;
        s2 += w2[64 + k] * e;
    }
    T1[z * HH + h] = s1;
    T2[z * HH + h] = s2;
}

__global__ void k_count(const int* __restrict__ pidx, int* __restrict__ cnt) {
    int p = blockIdx.x * 256 + threadIdx.x;
    if (p < N_PAIRS) atomicAdd(&cnt[pidx[p]], 1);
}

__global__ void k_scan(const int* __restrict__ cnt, int* __restrict__ offs, int* __restrict__ cur) {
    __shared__ int buf[1024];
    int tid = threadIdx.x;
    int base = tid * 10;
    int c[10]; int s = 0;
    #pragma unroll
    for (int i = 0; i < 10; ++i) {
        int idx = base + i;
        int v = (idx < N_ATOMS) ? cnt[idx] : 0;
        c[i] = v; s += v;
    }
    buf[tid] = s;
    __syncthreads();
    for (int off = 1; off < 1024; off <<= 1) {
        int v = (tid >= off) ? buf[tid - off] : 0;
        __syncthreads();
        buf[tid] += v;
        __syncthreads();
    }
    int run = buf[tid] - s;
    #pragma unroll
    for (int i = 0; i < 10; ++i) {
        int idx = base + i;
        if (idx < N_ATOMS) { offs[idx] = run; cur[idx] = run; run += c[i]; }
    }
    if (tid == 0) offs[N_ATOMS] = N_PAIRS;
}

__global__ void k_fill(const int* __restrict__ pidx, int* __restrict__ cur, int* __restrict__ plist) {
    int p = blockIdx.x * 256 + threadIdx.x;
    if (p < N_PAIRS) {
        int s = pidx[p];
        int pos = atomicAdd(&cur[s], 1);
        plist[pos] = p;
    }
}

__device__ __forceinline__ float dot4(float4 a, float4 b) {
    return a.x*b.x + a.y*b.y + a.z*b.z + a.w*b.w;
}

// 4 waves/block, one atom per wave. Pair loop is wave-synchronous (no block
// barriers — trip count differs per wave); epilogue uses __syncthreads (uniform).
__global__ __launch_bounds__(256, 2) void k_atom(
    const int* __restrict__ an, const int* __restrict__ pidx,
    const void* __restrict__ dij_v, const void* __restrict__ rij_v,
    const float* __restrict__ WF,
    const int* __restrict__ offs, const int* __restrict__ plist,
    const int* __restrict__ flags,
    const float* __restrict__ T1, const float* __restrict__ T2,
    float* __restrict__ out)
{
    const int wave = threadIdx.x >> 6;
    const int h    = threadIdx.x & 63;
    const int n    = blockIdx.x * 4 + wave;

    // per-wave LDS slice: rbf 32 | nv 64 | y1 128 | y2 192 | accL 640 | ob 576 = 1632 (+pad)
    __shared__ __align__(16) float lds[4 * 1664];
    float* rbf  = lds + wave * 1664;
    float* nv   = rbf + 32;
    float* y1   = nv + 64;
    float* y2   = y1 + 128;
    float* accL = y2 + 192;
    float* ob   = accL + 640;

    const bool dbf  = (flags[1] == 1);
    const bool rb16 = (flags[2] == 1);
    const float* dij_f = (const float*)dij_v;
    const float* rij_f = (const float*)rij_v;
    const unsigned short* dij_u = (const unsigned short*)dij_v;
    const unsigned short* rij_u = (const unsigned short*)rij_v;

    // loop-invariant per-lane dp rows -> registers (24 x float4)
    const float4* d1r = (const float4*)(WF + OFF_D1W) + h * 8;
    const float4* d2r = (const float4*)(WF + OFF_D2W) + h * 8;
    const float4* d3r = (const float4*)(WF + OFF_D3W) + h * 8;
    float4 A1[8], A2[8], A3[8];
    #pragma unroll
    for (int i = 0; i < 8; ++i) { A1[i] = d1r[i]; A2[i] = d2r[i]; A3[i] = d3r[i]; }

    const float ed1 = (WF + OFF_D1B)[h];
    const float ed2 = (WF + OFF_D2B)[h];
    const float ed3 = (WF + OFF_D3B)[h];
    // Zij[h] = eb2[h] + T1[z_src][h] + T2[z_dst][h]
    const float zA  = (WF + OFF_B2)[h] + T1[an[n] * HH + h];

    float Is=0.f, sx=0.f, sy=0.f, sz=0.f;
    float Sxx=0.f, Syy=0.f, Szz=0.f, Sxy=0.f, Sxz=0.f, Syz=0.f;

    const int pbeg = offs[n], pend = offs[n + 1];

    // software pipeline: prefetch pair metadata one iteration ahead
    int zn_n = 0; float d_n = 1.f, rx_n = 0.f, ry_n = 0.f, rz_n = 0.f;
    if (pbeg < pend) {
        int p = plist[pbeg];
        int dst = pidx[N_PAIRS + p];
        zn_n = an[dst];
        d_n = dbf ? bf2f(dij_u[p]) : dij_f[p];
        if (rb16) { rx_n = bf2f(rij_u[3*p]); ry_n = bf2f(rij_u[3*p+1]); rz_n = bf2f(rij_u[3*p+2]); }
        else      { rx_n = rij_f[3*p];       ry_n = rij_f[3*p+1];       rz_n = rij_f[3*p+2]; }
    }

    for (int ii = pbeg; ii < pend; ++ii) {
        const int   zn = zn_n;
        const float d  = d_n, rx = rx_n, ry = ry_n, rz = rz_n;
        if (ii + 1 < pend) {
            int p = plist[ii + 1];
            int dst = pidx[N_PAIRS + p];
            zn_n = an[dst];
            d_n = dbf ? bf2f(dij_u[p]) : dij_f[p];
            if (rb16) { rx_n = bf2f(rij_u[3*p]); ry_n = bf2f(rij_u[3*p+1]); rz_n = bf2f(rij_u[3*p+2]); }
            else      { rx_n = rij_f[3*p];       ry_n = rij_f[3*p+1];       rz_n = rij_f[3*p+2]; }
        }

        float inv = 1.0f / d;
        float ux = rx*inv, uy = ry*inv, uz = rz*inv;
        float rc = (d < 0.5f) ? 0.5f * (cosf(TWO_PI * d) + 1.0f) : 0.0f;

        if (h < 32) {
            float en = expf(-10.0f * d);
            float t = en - (RBF_START + RBF_STEP * (float)h);
            rbf[h] = expf(-RBF_BETA * t * t) * rc;
        }
        __builtin_amdgcn_wave_barrier();

        float zc = zA + T2[zn * HH + h];

        float g1 = ed1, g2 = ed2, g3 = ed3;
        const float4* rb4 = (const float4*)rbf;
        #pragma unroll
        for (int r4 = 0; r4 < 8; ++r4) {
            float4 rb = rb4[r4];
            g1 += dot4(A1[r4], rb);
            g2 += dot4(A2[r4], rb);
            g3 += dot4(A3[r4], rb);
        }
        float Cc = rc * zc;
        float f1 = g1 * Cc;
        float f2 = g2 * Cc * 10.0f;
        float f3 = g3 * Cc * 100.0f;

        Is += f1;
        sx += f2 * ux;  sy += f2 * uy;  sz += f2 * uz;
        float q = (ux*ux + uy*uy + uz*uz) * (1.0f / 3.0f);
        Sxx += f3 * (ux*ux - q);
        Syy += f3 * (uy*uy - q);
        Szz += f3 * (uz*uz - q);
        Sxy += f3 * (ux*uy);
        Sxz += f3 * (ux*uz);
        Syz += f3 * (uy*uz);
        __builtin_amdgcn_wave_barrier();
    }

    // ---- epilogue (uniform across waves; __syncthreads is safe here) ----
    accL[       h] = Is;
    accL[ 64  + h] = sx;  accL[128 + h] = sy;  accL[192 + h] = sz;
    accL[256 + h] = Sxx; accL[320 + h] = Syy; accL[384 + h] = Szz;
    accL[448 + h] = Sxy; accL[512 + h] = Sxz; accL[576 + h] = Syz;

    float tn = 3.0f*Is*Is + 2.0f*(sx*sx + sy*sy + sz*sz)
             + Sxx*Sxx + Syy*Syy + Szz*Szz
             + 2.0f*(Sxy*Sxy + Sxz*Sxz + Syz*Syz);

    float s1 = tn, s2 = tn * tn;
    #pragma unroll
    for (int o = 32; o > 0; o >>= 1) {
        s1 += __shfl_xor(s1, o);
        s2 += __shfl_xor(s2, o);
    }
    float mu  = s1 * (1.0f / 64.0f);
    float var = s2 * (1.0f / 64.0f) - mu * mu;
    float xh = (tn - mu) * rsqrtf(var + 1e-5f) * (WF + OFF_LNG)[h] + (WF + OFF_LNB)[h];
    nv[h] = xh;
    __syncthreads();

    #pragma unroll
    for (int jj = 0; jj < 2; ++jj) {
        int j = h + 64 * jj;
        const float4* wr = (const float4*)(WF + OFF_L1W) + j * 16;
        const float4* x4 = (const float4*)nv;
        float acc = (WF + OFF_L1B)[j];
        #pragma unroll
        for (int k4 = 0; k4 < 16; ++k4) acc += dot4(wr[k4], x4[k4]);
        y1[j] = acc / (1.0f + expf(-acc));
    }
    __syncthreads();

    #pragma unroll
    for (int mm = 0; mm < 3; ++mm) {
        int m = h + 64 * mm;
        const float4* wr = (const float4*)(WF + OFF_L2W) + m * 32;
        const float4* x4 = (const float4*)y1;
        float acc = (WF + OFF_L2B)[m];
        #pragma unroll
        for (int k4 = 0; k4 < 32; ++k4) acc += dot4(wr[k4], x4[k4]);
        y2[m] = acc / (1.0f + expf(-acc));
    }
    __syncthreads();

    float n0 = y2[3*h], n1 = y2[3*h+1], n2 = y2[3*h+2];
    const float4* t0r = (const float4*)(WF + OFF_LT0) + h * 16;
    const float4* t1r = (const float4*)(WF + OFF_LT1) + h * 16;
    const float4* t2r = (const float4*)(WF + OFF_LT2) + h * 16;
    const float4* aI  = (const float4*)(accL);
    const float4* aAx = (const float4*)(accL + 64);
    const float4* aAy = (const float4*)(accL + 128);
    const float4* aAz = (const float4*)(accL + 192);
    const float4* aXX = (const float4*)(accL + 256);
    const float4* aYY = (const float4*)(accL + 320);
    const float4* aZZ = (const float4*)(accL + 384);
    const float4* aXY = (const float4*)(accL + 448);
    const float4* aXZ = (const float4*)(accL + 512);
    const float4* aYZ = (const float4*)(accL + 576);

    float P0=0.f, PAx=0.f, PAy=0.f, PAz=0.f;
    float Q0=0.f, Q1=0.f, Q2=0.f, Q3=0.f, Q4=0.f, Q5=0.f;
    #pragma unroll
    for (int k4 = 0; k4 < 16; ++k4) {
        float4 w0 = t0r[k4], w1 = t1r[k4], w2 = t2r[k4];
        P0  += dot4(w0, aI[k4]);
        PAx += dot4(w1, aAx[k4]);
        PAy += dot4(w1, aAy[k4]);
        PAz += dot4(w1, aAz[k4]);
        Q0  += dot4(w2, aXX[k4]);
        Q1  += dot4(w2, aYY[k4]);
        Q2  += dot4(w2, aZZ[k4]);
        Q3  += dot4(w2, aXY[k4]);
        Q4  += dot4(w2, aXZ[k4]);
        Q5  += dot4(w2, aYZ[k4]);
    }
    float Iv = P0 * n0;
    float Ax = PAx * n1, Ay = PAy * n1, Az = PAz * n1;
    float Xx = Q0 * n2, Yy = Q1 * n2, Zz = Q2 * n2;
    float Xy = Q3 * n2, Xz = Q4 * n2, Yz = Q5 * n2;

    float* o = ob + h * 9;
    o[0] =  Iv + Xx;  o[1] = -Az + Xy;  o[2] =  Ay + Xz;
    o[3] =  Az + Xy;  o[4] =  Iv + Yy;  o[5] = -Ax + Yz;
    o[6] = -Ay + Xz;  o[7] =  Ax + Yz;  o[8] =  Iv + Zz;
    __syncthreads();

    float* outp = out + (size_t)n * 576;
    #pragma unroll
    for (int t = h; t < 576; t += 64) outp[t] = ob[t];
}

extern "C" void kernel_launch(void* const* d_in, const int* in_sizes, int n_in,
                              void* d_out, int out_size, void* d_ws, size_t ws_size,
                              hipStream_t stream) {
    const int* an   = (const int*)d_in[0];
    const int* pidx = (const int*)d_in[1];

    char* ws = (char*)d_ws;
    float* WF    = (float*)(ws + WS_WF);
    int*   cnt   = (int*)(ws + WS_CNT);
    int*   offs  = (int*)(ws + WS_OFF);
    int*   cur   = (int*)(ws + WS_CUR);
    int*   plist = (int*)(ws + WS_PLIST);
    int*   flags = (int*)(ws + WS_FLAGS);
    float* T1    = (float*)(ws + WS_T1);
    float* T2    = (float*)(ws + WS_T2);
    float* out   = (float*)d_out;

    hipMemsetAsync(cnt, 0, N_ATOMS * sizeof(int), stream);

    k_probe<<<1, 64, 0, stream>>>((const unsigned short*)d_in[4],
                                  (const unsigned short*)d_in[2],
                                  (const unsigned short*)d_in[3], flags);

    ConvArgs ca;
    for (int i = 0; i < 18; ++i) ca.src[i] = d_in[4 + i];
    ca.dst = WF;
    k_conv<<<(N_PARAMF + 255) / 256, 256, 0, stream>>>(ca, flags);
    k_tab<<<MAXZ, 64, 0, stream>>>(WF, T1, T2);

    k_count<<<(N_PAIRS + 255) / 256, 256, 0, stream>>>(pidx, cnt);
    k_scan<<<1, 1024, 0, stream>>>(cnt, offs, cur);
    k_fill<<<(N_PAIRS + 255) / 256, 256, 0, stream>>>(pidx, cur, plist);
    k_atom<<<2500, 256, 0, stream>>>(an, pidx, d_in[2], d_in[3], WF, offs, plist,
                                     flags, T1, T2, out);
}